// Round 5
// baseline (125.567 us; speedup 1.0000x reference)
//
#include <hip/hip_runtime.h>
#include <hip/hip_bf16.h>

typedef __attribute__((ext_vector_type(8))) short short8;
typedef __attribute__((ext_vector_type(4))) short short4v;
typedef __attribute__((ext_vector_type(4))) float float4v;

#define MFMA16(a,b,c) __builtin_amdgcn_mfma_f32_16x16x32_bf16((a),(b),(c),0,0,0)
#define EXP2(x) __builtin_amdgcn_exp2f(x)

static constexpr int Bz = 16, Sq = 1024, Dm = 384, Hh = 6, Dh = 64;
static constexpr int Mtok = Bz * Sq;     // 16384
static constexpr int NQKV = 1152;        // 3 * H * DH

__device__ __forceinline__ short f2bf(float f) {
  union { float f; unsigned u; } v; v.f = f;
  unsigned r = v.u + 0x7fffu + ((v.u >> 16) & 1u);  // RNE
  return (short)(r >> 16);
}

__device__ __forceinline__ void gload16(const void* src, void* lds) {
  __builtin_amdgcn_global_load_lds(
      (const __attribute__((address_space(1))) unsigned int*)src,
      (__attribute__((address_space(3))) unsigned int*)lds, 16, 0, 0);
}

// ---------------- prep: x fp32 -> bf16 ----------------
__global__ __launch_bounds__(256) void conv_x(const float* __restrict__ x,
                                              short* __restrict__ xb) {
  const int i = (blockIdx.x * 256 + threadIdx.x) * 8;  // total 6291456, exact
  float4v v0 = *(const float4v*)(x + i);
  float4v v1 = *(const float4v*)(x + i + 4);
  short8 o;
  o[0] = f2bf(v0[0]); o[1] = f2bf(v0[1]); o[2] = f2bf(v0[2]); o[3] = f2bf(v0[3]);
  o[4] = f2bf(v1[0]); o[5] = f2bf(v1[1]); o[6] = f2bf(v1[2]); o[7] = f2bf(v1[3]);
  *(short8*)(xb + i) = o;
}

// ---------------- prep: weights ----------------
__global__ __launch_bounds__(256) void conv_w(const float* __restrict__ Wq,
                                              const float* __restrict__ Wk,
                                              const float* __restrict__ Wv,
                                              const float* __restrict__ bq,
                                              const float* __restrict__ bk,
                                              const float* __restrict__ bv,
                                              const float* __restrict__ Wo,
                                              short* __restrict__ Wt,
                                              float* __restrict__ bias,
                                              short* __restrict__ Wob) {
  const float SCL = 0.125f * 1.44269504088896340736f;
  const int i = blockIdx.x * 256 + threadIdx.x;
  const int NW = NQKV * Dm;            // 442368
  if (i < NW) {
    const int c = i / Dm, d = i % Dm;
    const int p = c / 384, rr = c % 384;
    const int h = rr >> 6, dh = rr & 63;
    const float* W = (p == 0) ? Wq : ((p == 1) ? Wk : Wv);
    float w = W[(h * Dm + d) * Dh + dh];
    if (p == 0) w *= SCL;
    Wt[c * Dm + d] = f2bf(w);
  } else if (i < NW + NQKV) {
    const int c = i - NW;
    const int p = c / 384, rr = c % 384;
    const int h = rr >> 6, dh = rr & 63;
    const float* bb = (p == 0) ? bq : ((p == 1) ? bk : bv);
    float b = bb[h * Dh + dh];
    if (p == 0) b *= SCL;
    bias[c] = b;
  } else if (i < NW + NQKV + Dm * Dm) {
    const int j = i - NW - NQKV;
    Wob[j] = f2bf(Wo[j]);
  }
}

// LDS tile layout (GEMMs, BK=64): A[m 0..127][kb 0..127B] at row m, 128 B/row,
// colb = kb ^ ((m&7)<<4). Involution applied to global SOURCE during DMA
// (linear LDS dest, rule #21) and to the ds_read offset. Measured 0 bank
// conflicts with this scheme in R3/R4.

// ---------------- QKV GEMM v3: BK=64, 6 phases, 64KB LDS ----------------
__global__ __launch_bounds__(256) void qkv_gemm(const short* __restrict__ Xb,
                                                const short* __restrict__ Wt,
                                                const float* __restrict__ bias,
                                                short* __restrict__ qkv,
                                                short* __restrict__ vt) {
  __shared__ char smem[65536];  // 2 bufs x (16KB A + 16KB B)
  const int tid = threadIdx.x;
  const int wave = tid >> 6, lane = tid & 63;
  const int r = lane & 15, g = lane >> 4;
  const int xr = (r & 7) << 4;
  const int wr = wave >> 1, wc = wave & 1;

  // XCD-chunked bijective swizzle: nwg = 1152 = 8*144
  const int flat = blockIdx.x;
  const int w = (flat & 7) * 144 + (flat >> 3);
  const int bx = w % 9, by = w / 9;
  const int bm0 = by * 128, bn0 = bx * 128;
  const int m0 = bm0 + wr * 64, n0 = bn0 + wc * 64;

  float bv_n[4];
#pragma unroll
  for (int ni = 0; ni < 4; ++ni) bv_n[ni] = bias[n0 + ni * 16 + r];
  asm volatile("s_waitcnt vmcnt(0)" ::: "memory");

  // staging source pointers (pre-swizzled); 4 chunks x 16B per operand
  const char *aS[4], *bS[4];
#pragma unroll
  for (int j = 0; j < 4; ++j) {
    const int o = j * 4096 + tid * 16;
    const int lr = o >> 7;
    const int cb = (o & 127) ^ ((lr & 7) << 4);
    aS[j] = (const char*)(Xb + (bm0 + lr) * Dm) + cb;
    bS[j] = (const char*)(Wt + (bn0 + lr) * Dm) + cb;
  }
  auto stage = [&](int t, int buf) {
    char* base = smem + buf * 32768;
#pragma unroll
    for (int j = 0; j < 4; ++j) {
      gload16(aS[j] + t * 128, base + j * 4096 + tid * 16);
      gload16(bS[j] + t * 128, base + 16384 + j * 4096 + tid * 16);
    }
  };

  int aOff[4][2], bOff[4][2];
#pragma unroll
  for (int i = 0; i < 4; ++i)
#pragma unroll
    for (int c = 0; c < 2; ++c) {
      aOff[i][c] = (wr * 64 + i * 16 + r) * 128 + ((64 * c + 16 * g) ^ xr);
      bOff[i][c] = 16384 + (wc * 64 + i * 16 + r) * 128 + ((64 * c + 16 * g) ^ xr);
    }

  float4v acc[4][4] = {};
  auto compute = [&](int buf) {
    const char* sb = smem + buf * 32768;
    short8 a[4][2], b[4][2];
#pragma unroll
    for (int i = 0; i < 4; ++i) {
      a[i][0] = *(const short8*)(sb + aOff[i][0]);
      a[i][1] = *(const short8*)(sb + aOff[i][1]);
    }
#pragma unroll
    for (int i = 0; i < 4; ++i) {
      b[i][0] = *(const short8*)(sb + bOff[i][0]);
      b[i][1] = *(const short8*)(sb + bOff[i][1]);
    }
#pragma unroll
    for (int mi = 0; mi < 4; ++mi)
#pragma unroll
      for (int ni = 0; ni < 4; ++ni) {
        acc[mi][ni] = MFMA16(a[mi][0], b[ni][0], acc[mi][ni]);
        acc[mi][ni] = MFMA16(a[mi][1], b[ni][1], acc[mi][ni]);
      }
  };

  stage(0, 0);
  stage(1, 1);
  for (int t = 0; t < 5; ++t) {  // 6 K-steps total (K=384, BK=64)
    asm volatile("s_waitcnt vmcnt(8)" ::: "memory");
    __builtin_amdgcn_s_barrier();
    compute(t & 1);
    __builtin_amdgcn_s_barrier();
    if (t < 4) stage(t + 2, t & 1);
  }
  asm volatile("s_waitcnt vmcnt(0)" ::: "memory");
  __builtin_amdgcn_s_barrier();
  compute(1);

#pragma unroll
  for (int ni = 0; ni < 4; ++ni) {
    const int col = n0 + ni * 16 + r;
    const int p = col / 384, rr2 = col % 384;
    const int h = rr2 >> 6, dh = rr2 & 63;
    const float bv = bv_n[ni];
#pragma unroll
    for (int mi = 0; mi < 4; ++mi) {
#pragma unroll
      for (int reg = 0; reg < 4; ++reg) {
        const int mg = m0 + mi * 16 + 4 * g + reg;
        const short o = f2bf(acc[mi][ni][reg] + bv);
        if (p < 2) {
          qkv[mg * NQKV + col] = o;
        } else {
          const int bb = mg >> 10, s = mg & 1023;
          vt[((bb * Hh + h) * Dh + dh) * Sq + s] = o;
        }
      }
    }
  }
}

// ---------------- attention v4: KBLK=128, 8 phases, 64KB LDS ----------------
// K tile [128 kv][128B dh], V tile [64 dh][256B kv]; same involution swizzle.
// Compute is chunked per 32-kv (kk) to bound register liveness.
__global__ __launch_bounds__(256) void attn(const short* __restrict__ qkv,
                                            const short* __restrict__ vt,
                                            short* __restrict__ ctx) {
  __shared__ char smem[65536];  // 2 bufs x (16KB K + 16KB V)
  const int tid = threadIdx.x;
  const int wave = tid >> 6, lane = tid & 63;
  const int r = lane & 15, g = lane >> 4;
  const int xr = (r & 7) << 4;
  // XCD-chunked swizzle: nwg = 768 = 8*96
  const int flat = blockIdx.x;
  const int w = (flat & 7) * 96 + (flat >> 3);
  const int qb = w & 7, bh = w >> 3;
  const int b = bh / Hh, h = bh % Hh;
  const int tok0 = b * Sq;
  const int qw = qb * 128 + wave * 32;

  short8 qf[2][2];
#pragma unroll
  for (int f = 0; f < 2; ++f) {
    const short* qp = qkv + (tok0 + qw + 16 * f + r) * NQKV + h * Dh;
    qf[f][0] = *(const short8*)(qp + 8 * g);
    qf[f][1] = *(const short8*)(qp + 32 + 8 * g);
  }
  asm volatile("s_waitcnt vmcnt(0)" ::: "memory");  // drain Q before DMA counting

  const short* kg = qkv + tok0 * NQKV + 384 + h * Dh;  // K rows, stride NQKV
  const short* vg = vt + (b * Hh + h) * Dh * Sq;       // V^T rows, stride Sq

  // staging sources (pre-swizzled): K 4x16B, V 4x16B per thread per tile
  const char *kS[4], *vS[4];
#pragma unroll
  for (int j = 0; j < 4; ++j) {
    const int o = j * 4096 + tid * 16;
    const int kr = o >> 7;
    const int kcb = (o & 127) ^ ((kr & 7) << 4);
    kS[j] = (const char*)(kg + kr * NQKV) + kcb;
    const int vr = o >> 8;
    const int vcb = (o & 255) ^ ((vr & 7) << 4);
    vS[j] = (const char*)(vg + vr * Sq) + vcb;
  }
  auto stage = [&](int t, int buf) {
    char* base = smem + buf * 32768;
    const size_t krow = (size_t)t * 128 * NQKV * 2;  // 128 kv rows per tile
#pragma unroll
    for (int j = 0; j < 4; ++j) {
      gload16(kS[j] + krow, base + j * 4096 + tid * 16);
      gload16(vS[j] + t * 256, base + 16384 + j * 4096 + tid * 16);
    }
  };

  int kOff[8][2], vOff[4][4];
#pragma unroll
  for (int kt = 0; kt < 8; ++kt)
#pragma unroll
    for (int c = 0; c < 2; ++c)
      kOff[kt][c] = (16 * kt + r) * 128 + ((64 * c + 16 * g) ^ xr);
#pragma unroll
  for (int d = 0; d < 4; ++d)
#pragma unroll
    for (int kk = 0; kk < 4; ++kk)
      vOff[d][kk] = 16384 + (16 * d + r) * 256 + ((kk * 64 + 8 * g) ^ xr);

  float4v acc[4][2] = {};
  float lsum[2] = {0.f, 0.f};

  auto compute = [&](int buf) {
    const char* kb = smem + buf * 32768;
#pragma unroll
    for (int kk = 0; kk < 4; ++kk) {
      short8 kf0[2], kf1[2];
#pragma unroll
      for (int c = 0; c < 2; ++c) {
        kf0[c] = *(const short8*)(kb + kOff[2 * kk][c]);
        kf1[c] = *(const short8*)(kb + kOff[2 * kk + 1][c]);
      }
      float4v s0[2], s1[2];
#pragma unroll
      for (int f = 0; f < 2; ++f) {
        float4v z0 = {}, z1 = {};
        z0 = MFMA16(kf0[0], qf[f][0], z0);
        z0 = MFMA16(kf0[1], qf[f][1], z0);
        z1 = MFMA16(kf1[0], qf[f][0], z1);
        z1 = MFMA16(kf1[1], qf[f][1], z1);
        s0[f] = z0; s1[f] = z1;
      }
      short8 pa[2];
#pragma unroll
      for (int f = 0; f < 2; ++f) {
        float ps = 0.f;
#pragma unroll
        for (int j = 0; j < 4; ++j) {
          const float e0 = EXP2(s0[f][j]);
          const float e1 = EXP2(s1[f][j]);
          pa[f][j]     = f2bf(e0);
          pa[f][4 + j] = f2bf(e1);
          ps += e0 + e1;
        }
        lsum[f] += ps;
      }
#pragma unroll
      for (int d = 0; d < 4; ++d) {
        short4v lo = *(const short4v*)(kb + vOff[d][kk]);
        short4v hi = *(const short4v*)(kb + (vOff[d][kk] ^ 32));
        short8 vf;
        vf[0]=lo[0]; vf[1]=lo[1]; vf[2]=lo[2]; vf[3]=lo[3];
        vf[4]=hi[0]; vf[5]=hi[1]; vf[6]=hi[2]; vf[7]=hi[3];
        acc[d][0] = MFMA16(pa[0], vf, acc[d][0]);
        acc[d][1] = MFMA16(pa[1], vf, acc[d][1]);
      }
    }
  };

  stage(0, 0);
  stage(1, 1);
  for (int t = 0; t < 7; ++t) {  // 8 tiles of 128 kv
    asm volatile("s_waitcnt vmcnt(8)" ::: "memory");
    __builtin_amdgcn_s_barrier();
    compute(t & 1);
    __builtin_amdgcn_s_barrier();
    if (t < 6) stage(t + 2, t & 1);
  }
  asm volatile("s_waitcnt vmcnt(0)" ::: "memory");
  __builtin_amdgcn_s_barrier();
  compute(1);

#pragma unroll
  for (int f = 0; f < 2; ++f) {
    lsum[f] += __shfl_xor(lsum[f], 16);
    lsum[f] += __shfl_xor(lsum[f], 32);
  }
#pragma unroll
  for (int f = 0; f < 2; ++f) {
    float il[4];
#pragma unroll
    for (int reg = 0; reg < 4; ++reg) il[reg] = 1.f / __shfl(lsum[f], 4 * g + reg);
#pragma unroll
    for (int d = 0; d < 4; ++d) {
      short* cp = ctx + (tok0 + qw + 16 * f + 4 * g) * Dm + h * Dh + 16 * d + r;
#pragma unroll
      for (int reg = 0; reg < 4; ++reg)
        cp[reg * Dm] = f2bf(acc[d][f][reg] * il[reg]);
    }
  }
}

// ---------------- out-proj GEMM v3: BK=64, 6 phases ----------------
__global__ __launch_bounds__(256) void out_gemm(const short* __restrict__ ctx,
                                                const short* __restrict__ Wob,
                                                const float* __restrict__ bo,
                                                float* __restrict__ out) {
  __shared__ char smem[65536];
  const int tid = threadIdx.x;
  const int wave = tid >> 6, lane = tid & 63;
  const int r = lane & 15, g = lane >> 4;
  const int xr = (r & 7) << 4;
  const int wr = wave >> 1, wc = wave & 1;

  // XCD-chunked bijective swizzle: nwg = 384 = 8*48
  const int flat = blockIdx.x;
  const int w = (flat & 7) * 48 + (flat >> 3);
  const int bx = w % 3, by = w / 3;
  const int bm0 = by * 128, bn0 = bx * 128;
  const int m0 = bm0 + wr * 64, n0 = bn0 + wc * 64;

  float bv_n[4];
#pragma unroll
  for (int ni = 0; ni < 4; ++ni) bv_n[ni] = bo[n0 + ni * 16 + r];
  asm volatile("s_waitcnt vmcnt(0)" ::: "memory");

  const char *aS[4], *bS[4];
#pragma unroll
  for (int j = 0; j < 4; ++j) {
    const int o = j * 4096 + tid * 16;
    const int lr = o >> 7;
    const int cb = (o & 127) ^ ((lr & 7) << 4);
    aS[j] = (const char*)(ctx + (bm0 + lr) * Dm) + cb;
    bS[j] = (const char*)(Wob + (bn0 + lr) * Dm) + cb;
  }
  auto stage = [&](int t, int buf) {
    char* base = smem + buf * 32768;
#pragma unroll
    for (int j = 0; j < 4; ++j) {
      gload16(aS[j] + t * 128, base + j * 4096 + tid * 16);
      gload16(bS[j] + t * 128, base + 16384 + j * 4096 + tid * 16);
    }
  };

  int aOff[4][2], bOff[4][2];
#pragma unroll
  for (int i = 0; i < 4; ++i)
#pragma unroll
    for (int c = 0; c < 2; ++c) {
      aOff[i][c] = (wr * 64 + i * 16 + r) * 128 + ((64 * c + 16 * g) ^ xr);
      bOff[i][c] = 16384 + (wc * 64 + i * 16 + r) * 128 + ((64 * c + 16 * g) ^ xr);
    }

  float4v acc[4][4] = {};
  auto compute = [&](int buf) {
    const char* sb = smem + buf * 32768;
    short8 a[4][2], b[4][2];
#pragma unroll
    for (int i = 0; i < 4; ++i) {
      a[i][0] = *(const short8*)(sb + aOff[i][0]);
      a[i][1] = *(const short8*)(sb + aOff[i][1]);
    }
#pragma unroll
    for (int i = 0; i < 4; ++i) {
      b[i][0] = *(const short8*)(sb + bOff[i][0]);
      b[i][1] = *(const short8*)(sb + bOff[i][1]);
    }
#pragma unroll
    for (int mi = 0; mi < 4; ++mi)
#pragma unroll
      for (int ni = 0; ni < 4; ++ni) {
        acc[mi][ni] = MFMA16(a[mi][0], b[ni][0], acc[mi][ni]);
        acc[mi][ni] = MFMA16(a[mi][1], b[ni][1], acc[mi][ni]);
      }
  };

  stage(0, 0);
  stage(1, 1);
  for (int t = 0; t < 5; ++t) {
    asm volatile("s_waitcnt vmcnt(8)" ::: "memory");
    __builtin_amdgcn_s_barrier();
    compute(t & 1);
    __builtin_amdgcn_s_barrier();
    if (t < 4) stage(t + 2, t & 1);
  }
  asm volatile("s_waitcnt vmcnt(0)" ::: "memory");
  __builtin_amdgcn_s_barrier();
  compute(1);

#pragma unroll
  for (int ni = 0; ni < 4; ++ni) {
    const int col = n0 + ni * 16 + r;
    const float bv = bv_n[ni];
#pragma unroll
    for (int mi = 0; mi < 4; ++mi) {
#pragma unroll
      for (int reg = 0; reg < 4; ++reg) {
        const int mg = m0 + mi * 16 + 4 * g + reg;
        out[mg * Dm + col] = acc[mi][ni][reg] + bv;
      }
    }
  }
}

extern "C" void kernel_launch(void* const* d_in, const int* in_sizes, int n_in,
                              void* d_out, int out_size, void* d_ws, size_t ws_size,
                              hipStream_t stream) {
  const float* x  = (const float*)d_in[0];
  const float* Wq = (const float*)d_in[1];
  const float* bq = (const float*)d_in[2];
  const float* Wk = (const float*)d_in[3];
  const float* bk = (const float*)d_in[4];
  const float* Wv = (const float*)d_in[5];
  const float* bv = (const float*)d_in[6];
  const float* Wo = (const float*)d_in[7];
  const float* bo = (const float*)d_in[8];
  float* out = (float*)d_out;

  char* ws = (char*)d_ws;
  short* Xb   = (short*)(ws);                  // 16384*384*2   = 12,582,912
  short* Wt   = (short*)(ws + 12582912);       // 1152*384*2    =    884,736
  float* bias = (float*)(ws + 13467648);       // 1152*4        =      4,608
  short* Wob  = (short*)(ws + 13472256);       // 384*384*2     =    294,912
  short* qkv  = (short*)(ws + 13767168);       // 16384*1152*2  = 37,748,736
  short* vt   = (short*)(ws + 51515904);       // 16*6*64*1024*2= 12,582,912
  short* ctx  = (short*)(ws + 64098816);       // 16384*384*2   = 12,582,912
  // total 76,681,728 bytes

  conv_x<<<Mtok * Dm / (256 * 8), 256, 0, stream>>>(x, Xb);
  conv_w<<<(NQKV * Dm + NQKV + Dm * Dm + 255) / 256, 256, 0, stream>>>(
      Wq, Wk, Wv, bq, bk, bv, Wo, Wt, bias, Wob);
  qkv_gemm<<<1152, 256, 0, stream>>>(Xb, Wt, bias, qkv, vt);
  attn<<<768, 256, 0, stream>>>(qkv, vt, ctx);
  out_gemm<<<384, 256, 0, stream>>>(ctx, Wob, bo, out);
}

// Round 6
// 103.796 us; speedup vs baseline: 1.2097x; 1.2097x over previous
//
#include <hip/hip_runtime.h>
#include <hip/hip_bf16.h>

typedef __attribute__((ext_vector_type(8))) short short8;
typedef __attribute__((ext_vector_type(4))) short short4v;
typedef __attribute__((ext_vector_type(4))) float float4v;
typedef __attribute__((ext_vector_type(4))) int int4v;

#define MFMA16(a,b,c) __builtin_amdgcn_mfma_f32_16x16x32_bf16((a),(b),(c),0,0,0)
#define EXP2(x) __builtin_amdgcn_exp2f(x)

static constexpr int Bz = 16, Sq = 1024, Dm = 384, Hh = 6, Dh = 64;
static constexpr int Mtok = Bz * Sq;     // 16384
static constexpr int NQKV = 1152;        // 3 * H * DH

__device__ __forceinline__ short f2bf(float f) {
  union { float f; unsigned u; } v; v.f = f;
  unsigned r = v.u + 0x7fffu + ((v.u >> 16) & 1u);  // RNE
  return (short)(r >> 16);
}

// packed f32x2 -> bf16x2 (lo = a, hi = b), RNE in HW
__device__ __forceinline__ unsigned cvtpk(float a, float b) {
  unsigned d;
  asm("v_cvt_pk_bf16_f32 %0, %1, %2" : "=v"(d) : "v"(a), "v"(b));
  return d;
}

__device__ __forceinline__ void gload16(const void* src, void* lds) {
  __builtin_amdgcn_global_load_lds(
      (const __attribute__((address_space(1))) unsigned int*)src,
      (__attribute__((address_space(3))) unsigned int*)lds, 16, 0, 0);
}

// ---------------- prep: x fp32 -> bf16 ----------------
__global__ __launch_bounds__(256) void conv_x(const float* __restrict__ x,
                                              short* __restrict__ xb) {
  const int i = (blockIdx.x * 256 + threadIdx.x) * 8;  // total 6291456, exact
  float4v v0 = *(const float4v*)(x + i);
  float4v v1 = *(const float4v*)(x + i + 4);
  short8 o;
  o[0] = f2bf(v0[0]); o[1] = f2bf(v0[1]); o[2] = f2bf(v0[2]); o[3] = f2bf(v0[3]);
  o[4] = f2bf(v1[0]); o[5] = f2bf(v1[1]); o[6] = f2bf(v1[2]); o[7] = f2bf(v1[3]);
  *(short8*)(xb + i) = o;
}

// ---------------- prep: weights ----------------
__global__ __launch_bounds__(256) void conv_w(const float* __restrict__ Wq,
                                              const float* __restrict__ Wk,
                                              const float* __restrict__ Wv,
                                              const float* __restrict__ bq,
                                              const float* __restrict__ bk,
                                              const float* __restrict__ bv,
                                              const float* __restrict__ Wo,
                                              short* __restrict__ Wt,
                                              float* __restrict__ bias,
                                              short* __restrict__ Wob) {
  const float SCL = 0.125f * 1.44269504088896340736f;
  const int i = blockIdx.x * 256 + threadIdx.x;
  const int NW = NQKV * Dm;            // 442368
  if (i < NW) {
    const int c = i / Dm, d = i % Dm;
    const int p = c / 384, rr = c % 384;
    const int h = rr >> 6, dh = rr & 63;
    const float* W = (p == 0) ? Wq : ((p == 1) ? Wk : Wv);
    float w = W[(h * Dm + d) * Dh + dh];
    if (p == 0) w *= SCL;
    Wt[c * Dm + d] = f2bf(w);
  } else if (i < NW + NQKV) {
    const int c = i - NW;
    const int p = c / 384, rr = c % 384;
    const int h = rr >> 6, dh = rr & 63;
    const float* bb = (p == 0) ? bq : ((p == 1) ? bk : bv);
    float b = bb[h * Dh + dh];
    if (p == 0) b *= SCL;
    bias[c] = b;
  } else if (i < NW + NQKV + Dm * Dm) {
    const int j = i - NW - NQKV;
    Wob[j] = f2bf(Wo[j]);
  }
}

// LDS tile layout (GEMMs, BK=32): A[m 0..127][kb 0..63B] at lrow=m>>1,
// colb = (((m&1)<<6)|kb) ^ ((lrow&7)<<4). Involution applied to the global
// SOURCE during DMA (linear LDS dest, rule #21) and to the ds_read offset.
// Measured 0 bank conflicts (R4).

// ---------------- QKV GEMM v4: BK=32, 3-deep pipeline, 48KB LDS ----------------
__global__ __launch_bounds__(256) void qkv_gemm(const short* __restrict__ Xb,
                                                const short* __restrict__ Wt,
                                                const float* __restrict__ bias,
                                                short* __restrict__ qkv,
                                                short* __restrict__ vt) {
  __shared__ char smem[49152];  // 3 bufs x (8KB A + 8KB B)
  const int tid = threadIdx.x;
  const int wave = tid >> 6, lane = tid & 63;
  const int r = lane & 15, g = lane >> 4;
  const int wr = wave >> 1, wc = wave & 1;

  // XCD-chunked bijective swizzle: nwg = 1152 = 8*144
  const int flat = blockIdx.x;
  const int w = (flat & 7) * 144 + (flat >> 3);
  const int bx = w % 9, by = w / 9;
  const int bm0 = by * 128, bn0 = bx * 128;
  const int m0 = bm0 + wr * 64, n0 = bn0 + wc * 64;

  float bv_n[4];
#pragma unroll
  for (int ni = 0; ni < 4; ++ni) bv_n[ni] = bias[n0 + ni * 16 + r];
  asm volatile("s_waitcnt vmcnt(0)" ::: "memory");

  // staging source pointers (pre-swizzled)
  const char *aSrc0, *aSrc1, *bSrc0, *bSrc1;
  {
    const int o0 = tid * 16, o1 = 4096 + tid * 16;
    const int lr0 = o0 >> 7, cb0 = (o0 & 127) ^ ((lr0 & 7) << 4);
    const int lr1 = o1 >> 7, cb1 = (o1 & 127) ^ ((lr1 & 7) << 4);
    const int m_0 = 2 * lr0 + (cb0 >> 6), kb0 = cb0 & 63;
    const int m_1 = 2 * lr1 + (cb1 >> 6), kb1 = cb1 & 63;
    aSrc0 = (const char*)(Xb + (bm0 + m_0) * Dm) + kb0;
    aSrc1 = (const char*)(Xb + (bm0 + m_1) * Dm) + kb1;
    bSrc0 = (const char*)(Wt + (bn0 + m_0) * Dm) + kb0;
    bSrc1 = (const char*)(Wt + (bn0 + m_1) * Dm) + kb1;
  }
  auto stage = [&](int t, int buf) {
    char* base = smem + buf * 16384;
    const int kb = t * 64;
    gload16(aSrc0 + kb, base + wave * 1024);
    gload16(aSrc1 + kb, base + 4096 + wave * 1024);
    gload16(bSrc0 + kb, base + 8192 + wave * 1024);
    gload16(bSrc1 + kb, base + 12288 + wave * 1024);
  };

  int aOff[4], bOff[4];
#pragma unroll
  for (int i = 0; i < 4; ++i) {
    const int m = wr * 64 + i * 16 + r;
    const int lr = m >> 1;
    aOff[i] = lr * 128 + ((((m & 1) << 6) | (16 * g)) ^ ((lr & 7) << 4));
    const int n = wc * 64 + i * 16 + r;
    const int lrn = n >> 1;
    bOff[i] = 8192 + lrn * 128 + ((((n & 1) << 6) | (16 * g)) ^ ((lrn & 7) << 4));
  }

  float4v acc[4][4] = {};
  auto compute = [&](int buf) {
    const char* sb = smem + buf * 16384;
    short8 a[4], b[4];
#pragma unroll
    for (int i = 0; i < 4; ++i) a[i] = *(const short8*)(sb + aOff[i]);
#pragma unroll
    for (int i = 0; i < 4; ++i) b[i] = *(const short8*)(sb + bOff[i]);
#pragma unroll
    for (int mi = 0; mi < 4; ++mi)
#pragma unroll
      for (int ni = 0; ni < 4; ++ni)
        acc[mi][ni] = MFMA16(a[mi], b[ni], acc[mi][ni]);
  };

  stage(0, 0);
  stage(1, 1);
  stage(2, 2);
#pragma unroll 1
  for (int t = 0; t < 10; ++t) {  // 12 K-steps total
    asm volatile("s_waitcnt vmcnt(8)" ::: "memory");
    __builtin_amdgcn_s_barrier();
    compute(t % 3);
    __builtin_amdgcn_s_barrier();
    if (t < 9) stage(t + 3, t % 3);
  }
  asm volatile("s_waitcnt vmcnt(4)" ::: "memory");
  __builtin_amdgcn_s_barrier();
  compute(1);
  asm volatile("s_waitcnt vmcnt(0)" ::: "memory");
  __builtin_amdgcn_s_barrier();
  compute(2);

#pragma unroll
  for (int ni = 0; ni < 4; ++ni) {
    const int col = n0 + ni * 16 + r;
    const int p = col / 384, rr2 = col % 384;
    const int h = rr2 >> 6, dh = rr2 & 63;
    const float bv = bv_n[ni];
#pragma unroll
    for (int mi = 0; mi < 4; ++mi) {
#pragma unroll
      for (int rp = 0; rp < 2; ++rp) {
        const unsigned u = cvtpk(acc[mi][ni][2 * rp] + bv,
                                 acc[mi][ni][2 * rp + 1] + bv);
        const short lo = (short)u, hi = (short)(u >> 16);
        const int mg = m0 + mi * 16 + 4 * g + 2 * rp;
        if (p < 2) {
          qkv[mg * NQKV + col] = lo;
          qkv[(mg + 1) * NQKV + col] = hi;
        } else {
          const int bb = mg >> 10, s = mg & 1023;
          short* vp = vt + ((bb * Hh + h) * Dh + dh) * Sq;
          vp[s] = lo;
          vp[s + 1] = hi;  // mg+1 same b (128-row tiles never straddle)
        }
      }
    }
  }
}

// ---------------- attention v5: R4 structure + cvt_pk softmax + setprio ------
// grid 768; 4 waves x 32 q-rows; KBLK=64; 2-buf 32KB LDS; vmcnt(4).
__global__ __launch_bounds__(256) void attn(const short* __restrict__ qkv,
                                            const short* __restrict__ vt,
                                            short* __restrict__ ctx) {
  __shared__ char smem[32768];  // 2 bufs x (8KB K + 8KB V)
  const int tid = threadIdx.x;
  const int wave = tid >> 6, lane = tid & 63;
  const int r = lane & 15, g = lane >> 4;
  const int xr = (r & 7) << 4;
  // XCD-chunked swizzle: nwg = 768 = 8*96
  const int flat = blockIdx.x;
  const int w = (flat & 7) * 96 + (flat >> 3);
  const int qb = w & 7, bh = w >> 3;
  const int b = bh / Hh, h = bh % Hh;
  const int tok0 = b * Sq;
  const int qw = qb * 128 + wave * 32;

  short8 qf[2][2];
#pragma unroll
  for (int f = 0; f < 2; ++f) {
    const short* qp = qkv + (tok0 + qw + 16 * f + r) * NQKV + h * Dh;
    qf[f][0] = *(const short8*)(qp + 8 * g);
    qf[f][1] = *(const short8*)(qp + 32 + 8 * g);
  }
  asm volatile("s_waitcnt vmcnt(0)" ::: "memory");  // drain Q before DMA counting

  const short* kg = qkv + tok0 * NQKV + 384 + h * Dh;  // K rows, stride NQKV
  const short* vg = vt + (b * Hh + h) * Dh * Sq;       // V^T rows, stride Sq

  const int o0 = wave * 2048 + lane * 16;
  const int row0 = o0 >> 7, cb0 = (o0 & 127) ^ ((row0 & 7) << 4);
  const int o1 = o0 + 1024;
  const int row1 = o1 >> 7, cb1 = (o1 & 127) ^ ((row1 & 7) << 4);

#define STAGE(T, BUFSEL)                                                        \
  {                                                                             \
    char* kb_ = smem + (BUFSEL) * 16384;                                        \
    const int kv_ = (T) * 64;                                                   \
    gload16((const char*)(kg + (kv_ + row0) * NQKV) + cb0, kb_ + wave * 2048);  \
    gload16((const char*)(vg + row0 * Sq + kv_) + cb0, kb_ + 8192 + wave * 2048);\
    gload16((const char*)(kg + (kv_ + row1) * NQKV) + cb1, kb_ + wave * 2048 + 1024);\
    gload16((const char*)(vg + row1 * Sq + kv_) + cb1, kb_ + 8192 + wave * 2048 + 1024);\
  }

  int kOff[4][2], vOff[4][2];
#pragma unroll
  for (int kt = 0; kt < 4; ++kt)
#pragma unroll
    for (int c = 0; c < 2; ++c)
      kOff[kt][c] = (16 * kt + r) * 128 + ((64 * c + 16 * g) ^ xr);
#pragma unroll
  for (int d = 0; d < 4; ++d)
#pragma unroll
    for (int h2 = 0; h2 < 2; ++h2)
      vOff[d][h2] = (16 * d + r) * 128 + ((64 * h2 + 8 * g) ^ xr);

  float4v acc[4][2] = {};
  float lsum[2] = {0.f, 0.f};

  auto compute = [&](int bufsel) {
    const char* kb = smem + bufsel * 16384;
    const char* vb = kb + 8192;
    short8 kf[4][2];
#pragma unroll
    for (int kt = 0; kt < 4; ++kt) {
      kf[kt][0] = *(const short8*)(kb + kOff[kt][0]);
      kf[kt][1] = *(const short8*)(kb + kOff[kt][1]);
    }
    short8 vf[4][2];
#pragma unroll
    for (int d = 0; d < 4; ++d)
#pragma unroll
      for (int h2 = 0; h2 < 2; ++h2) {
        short4v lo = *(const short4v*)(vb + vOff[d][h2]);
        short4v hi = *(const short4v*)(vb + (vOff[d][h2] ^ 32));
        short8 t;
        t[0] = lo[0]; t[1] = lo[1]; t[2] = lo[2]; t[3] = lo[3];
        t[4] = hi[0]; t[5] = hi[1]; t[6] = hi[2]; t[7] = hi[3];
        vf[d][h2] = t;
      }
    float4v s[4][2];
    __builtin_amdgcn_s_setprio(1);
#pragma unroll
    for (int kt = 0; kt < 4; ++kt)
#pragma unroll
      for (int f = 0; f < 2; ++f) {
        float4v z = {};
        z = MFMA16(kf[kt][0], qf[f][0], z);
        z = MFMA16(kf[kt][1], qf[f][1], z);
        s[kt][f] = z;
      }
    __builtin_amdgcn_s_setprio(0);
    short8 pa[2][2];
#pragma unroll
    for (int f = 0; f < 2; ++f) {
      float ps = 0.f;
#pragma unroll
      for (int h2 = 0; h2 < 2; ++h2) {
        float e0[4], e1[4];
#pragma unroll
        for (int j = 0; j < 4; ++j) {
          e0[j] = EXP2(s[2 * h2][f][j]);
          e1[j] = EXP2(s[2 * h2 + 1][f][j]);
          ps += e0[j] + e1[j];
        }
        int4v wv;
        wv[0] = (int)cvtpk(e0[0], e0[1]);
        wv[1] = (int)cvtpk(e0[2], e0[3]);
        wv[2] = (int)cvtpk(e1[0], e1[1]);
        wv[3] = (int)cvtpk(e1[2], e1[3]);
        pa[f][h2] = __builtin_bit_cast(short8, wv);
      }
      lsum[f] += ps;
    }
    __builtin_amdgcn_s_setprio(1);
#pragma unroll
    for (int d = 0; d < 4; ++d)
#pragma unroll
      for (int f = 0; f < 2; ++f) {
        acc[d][f] = MFMA16(pa[f][0], vf[d][0], acc[d][f]);
        acc[d][f] = MFMA16(pa[f][1], vf[d][1], acc[d][f]);
      }
    __builtin_amdgcn_s_setprio(0);
  };

  STAGE(0, 0)
  STAGE(1, 1)
#pragma unroll 1
  for (int t = 0; t < 15; ++t) {
    asm volatile("s_waitcnt vmcnt(4)" ::: "memory");
    __builtin_amdgcn_s_barrier();
    compute(t & 1);
    __builtin_amdgcn_s_barrier();
    if (t < 14) STAGE(t + 2, t & 1)
  }
  asm volatile("s_waitcnt vmcnt(0)" ::: "memory");
  __builtin_amdgcn_s_barrier();
  compute(1);

#pragma unroll
  for (int f = 0; f < 2; ++f) {
    lsum[f] += __shfl_xor(lsum[f], 16);
    lsum[f] += __shfl_xor(lsum[f], 32);
  }
#pragma unroll
  for (int f = 0; f < 2; ++f) {
    float il[4];
#pragma unroll
    for (int reg = 0; reg < 4; ++reg) il[reg] = 1.f / __shfl(lsum[f], 4 * g + reg);
#pragma unroll
    for (int d = 0; d < 4; ++d) {
      short* cp = ctx + (tok0 + qw + 16 * f + 4 * g) * Dm + h * Dh + 16 * d + r;
#pragma unroll
      for (int reg = 0; reg < 4; ++reg)
        cp[reg * Dm] = f2bf(acc[d][f][reg] * il[reg]);
    }
  }
}

// ---------------- out-proj GEMM v4: BK=32, 3-deep pipeline ----------------
__global__ __launch_bounds__(256) void out_gemm(const short* __restrict__ ctx,
                                                const short* __restrict__ Wob,
                                                const float* __restrict__ bo,
                                                float* __restrict__ out) {
  __shared__ char smem[49152];
  const int tid = threadIdx.x;
  const int wave = tid >> 6, lane = tid & 63;
  const int r = lane & 15, g = lane >> 4;
  const int wr = wave >> 1, wc = wave & 1;

  // XCD-chunked bijective swizzle: nwg = 384 = 8*48
  const int flat = blockIdx.x;
  const int w = (flat & 7) * 48 + (flat >> 3);
  const int bx = w % 3, by = w / 3;
  const int bm0 = by * 128, bn0 = bx * 128;
  const int m0 = bm0 + wr * 64, n0 = bn0 + wc * 64;

  float bv_n[4];
#pragma unroll
  for (int ni = 0; ni < 4; ++ni) bv_n[ni] = bo[n0 + ni * 16 + r];
  asm volatile("s_waitcnt vmcnt(0)" ::: "memory");

  const char *aSrc0, *aSrc1, *bSrc0, *bSrc1;
  {
    const int o0 = tid * 16, o1 = 4096 + tid * 16;
    const int lr0 = o0 >> 7, cb0 = (o0 & 127) ^ ((lr0 & 7) << 4);
    const int lr1 = o1 >> 7, cb1 = (o1 & 127) ^ ((lr1 & 7) << 4);
    const int m_0 = 2 * lr0 + (cb0 >> 6), kb0 = cb0 & 63;
    const int m_1 = 2 * lr1 + (cb1 >> 6), kb1 = cb1 & 63;
    aSrc0 = (const char*)(ctx + (bm0 + m_0) * Dm) + kb0;
    aSrc1 = (const char*)(ctx + (bm0 + m_1) * Dm) + kb1;
    bSrc0 = (const char*)(Wob + (bn0 + m_0) * Dm) + kb0;
    bSrc1 = (const char*)(Wob + (bn0 + m_1) * Dm) + kb1;
  }
  auto stage = [&](int t, int buf) {
    char* base = smem + buf * 16384;
    const int kb = t * 64;
    gload16(aSrc0 + kb, base + wave * 1024);
    gload16(aSrc1 + kb, base + 4096 + wave * 1024);
    gload16(bSrc0 + kb, base + 8192 + wave * 1024);
    gload16(bSrc1 + kb, base + 12288 + wave * 1024);
  };

  int aOff[4], bOff[4];
#pragma unroll
  for (int i = 0; i < 4; ++i) {
    const int m = wr * 64 + i * 16 + r;
    const int lr = m >> 1;
    aOff[i] = lr * 128 + ((((m & 1) << 6) | (16 * g)) ^ ((lr & 7) << 4));
    const int n = wc * 64 + i * 16 + r;
    const int lrn = n >> 1;
    bOff[i] = 8192 + lrn * 128 + ((((n & 1) << 6) | (16 * g)) ^ ((lrn & 7) << 4));
  }

  float4v acc[4][4] = {};
  auto compute = [&](int buf) {
    const char* sb = smem + buf * 16384;
    short8 a[4], b[4];
#pragma unroll
    for (int i = 0; i < 4; ++i) a[i] = *(const short8*)(sb + aOff[i]);
#pragma unroll
    for (int i = 0; i < 4; ++i) b[i] = *(const short8*)(sb + bOff[i]);
#pragma unroll
    for (int mi = 0; mi < 4; ++mi)
#pragma unroll
      for (int ni = 0; ni < 4; ++ni)
        acc[mi][ni] = MFMA16(a[mi], b[ni], acc[mi][ni]);
  };

  stage(0, 0);
  stage(1, 1);
  stage(2, 2);
#pragma unroll 1
  for (int t = 0; t < 10; ++t) {
    asm volatile("s_waitcnt vmcnt(8)" ::: "memory");
    __builtin_amdgcn_s_barrier();
    compute(t % 3);
    __builtin_amdgcn_s_barrier();
    if (t < 9) stage(t + 3, t % 3);
  }
  asm volatile("s_waitcnt vmcnt(4)" ::: "memory");
  __builtin_amdgcn_s_barrier();
  compute(1);
  asm volatile("s_waitcnt vmcnt(0)" ::: "memory");
  __builtin_amdgcn_s_barrier();
  compute(2);

#pragma unroll
  for (int ni = 0; ni < 4; ++ni) {
    const int col = n0 + ni * 16 + r;
    const float bv = bv_n[ni];
#pragma unroll
    for (int mi = 0; mi < 4; ++mi) {
#pragma unroll
      for (int reg = 0; reg < 4; ++reg) {
        const int mg = m0 + mi * 16 + 4 * g + reg;
        out[mg * Dm + col] = acc[mi][ni][reg] + bv;
      }
    }
  }
}

extern "C" void kernel_launch(void* const* d_in, const int* in_sizes, int n_in,
                              void* d_out, int out_size, void* d_ws, size_t ws_size,
                              hipStream_t stream) {
  const float* x  = (const float*)d_in[0];
  const float* Wq = (const float*)d_in[1];
  const float* bq = (const float*)d_in[2];
  const float* Wk = (const float*)d_in[3];
  const float* bk = (const float*)d_in[4];
  const float* Wv = (const float*)d_in[5];
  const float* bv = (const float*)d_in[6];
  const float* Wo = (const float*)d_in[7];
  const float* bo = (const float*)d_in[8];
  float* out = (float*)d_out;

  char* ws = (char*)d_ws;
  short* Xb   = (short*)(ws);                  // 16384*384*2   = 12,582,912
  short* Wt   = (short*)(ws + 12582912);       // 1152*384*2    =    884,736
  float* bias = (float*)(ws + 13467648);       // 1152*4        =      4,608
  short* Wob  = (short*)(ws + 13472256);       // 384*384*2     =    294,912
  short* qkv  = (short*)(ws + 13767168);       // 16384*1152*2  = 37,748,736
  short* vt   = (short*)(ws + 51515904);       // 16*6*64*1024*2= 12,582,912
  short* ctx  = (short*)(ws + 64098816);       // 16384*384*2   = 12,582,912
  // total 76,681,728 bytes

  conv_x<<<Mtok * Dm / (256 * 8), 256, 0, stream>>>(x, Xb);
  conv_w<<<(NQKV * Dm + NQKV + Dm * Dm + 255) / 256, 256, 0, stream>>>(
      Wq, Wk, Wv, bq, bk, bv, Wo, Wt, bias, Wob);
  qkv_gemm<<<1152, 256, 0, stream>>>(Xb, Wt, bias, qkv, vt);
  attn<<<768, 256, 0, stream>>>(qkv, vt, ctx);
  out_gemm<<<384, 256, 0, stream>>>(ctx, Wob, bo, out);
}

// Round 7
// 100.383 us; speedup vs baseline: 1.2509x; 1.0340x over previous
//
#include <hip/hip_runtime.h>
#include <hip/hip_bf16.h>

typedef __attribute__((ext_vector_type(8))) short short8;
typedef __attribute__((ext_vector_type(4))) short short4v;
typedef __attribute__((ext_vector_type(4))) float float4v;
typedef __attribute__((ext_vector_type(4))) int int4v;

#define MFMA16(a,b,c) __builtin_amdgcn_mfma_f32_16x16x32_bf16((a),(b),(c),0,0,0)
#define EXP2(x) __builtin_amdgcn_exp2f(x)

static constexpr int Bz = 16, Sq = 1024, Dm = 384, Hh = 6, Dh = 64;
static constexpr int Mtok = Bz * Sq;     // 16384
static constexpr int NQKV = 1152;        // 3 * H * DH

__device__ __forceinline__ short f2bf(float f) {
  union { float f; unsigned u; } v; v.f = f;
  unsigned r = v.u + 0x7fffu + ((v.u >> 16) & 1u);  // RNE
  return (short)(r >> 16);
}

// packed f32x2 -> bf16x2 (lo = a, hi = b), RNE in HW
__device__ __forceinline__ unsigned cvtpk(float a, float b) {
  unsigned d;
  asm("v_cvt_pk_bf16_f32 %0, %1, %2" : "=v"(d) : "v"(a), "v"(b));
  return d;
}

__device__ __forceinline__ void gload16(const void* src, void* lds) {
  __builtin_amdgcn_global_load_lds(
      (const __attribute__((address_space(1))) unsigned int*)src,
      (__attribute__((address_space(3))) unsigned int*)lds, 16, 0, 0);
}

// kv-permutation within each 32-block: loc = 16hi+4grp+e -> 8grp+4hi+e.
// Makes each lane's PV B-fragment (orig kv {4g..4g+3} u {16+4g..19+4g})
// 16 CONTIGUOUS bytes -> single conflict-free ds_read_b128 in attn.
__device__ __forceinline__ int vperm(int s) {
  return (s & ~31) | ((s & 12) << 1) | ((s & 16) >> 2) | (s & 3);
}

// ---------------- prep: x fp32 -> bf16 ----------------
__global__ __launch_bounds__(256) void conv_x(const float* __restrict__ x,
                                              short* __restrict__ xb) {
  const int i = (blockIdx.x * 256 + threadIdx.x) * 8;  // total 6291456, exact
  float4v v0 = *(const float4v*)(x + i);
  float4v v1 = *(const float4v*)(x + i + 4);
  short8 o;
  o[0] = f2bf(v0[0]); o[1] = f2bf(v0[1]); o[2] = f2bf(v0[2]); o[3] = f2bf(v0[3]);
  o[4] = f2bf(v1[0]); o[5] = f2bf(v1[1]); o[6] = f2bf(v1[2]); o[7] = f2bf(v1[3]);
  *(short8*)(xb + i) = o;
}

// ---------------- prep: weights ----------------
__global__ __launch_bounds__(256) void conv_w(const float* __restrict__ Wq,
                                              const float* __restrict__ Wk,
                                              const float* __restrict__ Wv,
                                              const float* __restrict__ bq,
                                              const float* __restrict__ bk,
                                              const float* __restrict__ bv,
                                              const float* __restrict__ Wo,
                                              short* __restrict__ Wt,
                                              float* __restrict__ bias,
                                              short* __restrict__ Wob) {
  const float SCL = 0.125f * 1.44269504088896340736f;
  const int i = blockIdx.x * 256 + threadIdx.x;
  const int NW = NQKV * Dm;            // 442368
  if (i < NW) {
    const int c = i / Dm, d = i % Dm;
    const int p = c / 384, rr = c % 384;
    const int h = rr >> 6, dh = rr & 63;
    const float* W = (p == 0) ? Wq : ((p == 1) ? Wk : Wv);
    float w = W[(h * Dm + d) * Dh + dh];
    if (p == 0) w *= SCL;
    Wt[c * Dm + d] = f2bf(w);
  } else if (i < NW + NQKV) {
    const int c = i - NW;
    const int p = c / 384, rr = c % 384;
    const int h = rr >> 6, dh = rr & 63;
    const float* bb = (p == 0) ? bq : ((p == 1) ? bk : bv);
    float b = bb[h * Dh + dh];
    if (p == 0) b *= SCL;
    bias[c] = b;
  } else if (i < NW + NQKV + Dm * Dm) {
    const int j = i - NW - NQKV;
    Wob[j] = f2bf(Wo[j]);
  }
}

// LDS tile layout (GEMMs, BK=32): A[m 0..127][kb 0..63B] at lrow=m>>1,
// colb = (((m&1)<<6)|kb) ^ ((lrow&7)<<4). Involution applied to the global
// SOURCE during DMA (linear LDS dest, rule #21) and to the ds_read offset.
// Measured 0 bank conflicts (R4).

// ---------------- QKV GEMM v5: BK=32, 3-deep pipeline, 48KB LDS ----------------
__global__ __launch_bounds__(256) void qkv_gemm(const short* __restrict__ Xb,
                                                const short* __restrict__ Wt,
                                                const float* __restrict__ bias,
                                                short* __restrict__ qkv,
                                                short* __restrict__ vt) {
  __shared__ char smem[49152];  // 3 bufs x (8KB A + 8KB B)
  const int tid = threadIdx.x;
  const int wave = tid >> 6, lane = tid & 63;
  const int r = lane & 15, g = lane >> 4;
  const int wr = wave >> 1, wc = wave & 1;

  // XCD-chunked bijective swizzle: nwg = 1152 = 8*144
  const int flat = blockIdx.x;
  const int w = (flat & 7) * 144 + (flat >> 3);
  const int bx = w % 9, by = w / 9;
  const int bm0 = by * 128, bn0 = bx * 128;
  const int m0 = bm0 + wr * 64, n0 = bn0 + wc * 64;

  float bv_n[4];
#pragma unroll
  for (int ni = 0; ni < 4; ++ni) bv_n[ni] = bias[n0 + ni * 16 + r];
  asm volatile("s_waitcnt vmcnt(0)" ::: "memory");

  // staging source pointers (pre-swizzled)
  const char *aSrc0, *aSrc1, *bSrc0, *bSrc1;
  {
    const int o0 = tid * 16, o1 = 4096 + tid * 16;
    const int lr0 = o0 >> 7, cb0 = (o0 & 127) ^ ((lr0 & 7) << 4);
    const int lr1 = o1 >> 7, cb1 = (o1 & 127) ^ ((lr1 & 7) << 4);
    const int m_0 = 2 * lr0 + (cb0 >> 6), kb0 = cb0 & 63;
    const int m_1 = 2 * lr1 + (cb1 >> 6), kb1 = cb1 & 63;
    aSrc0 = (const char*)(Xb + (bm0 + m_0) * Dm) + kb0;
    aSrc1 = (const char*)(Xb + (bm0 + m_1) * Dm) + kb1;
    bSrc0 = (const char*)(Wt + (bn0 + m_0) * Dm) + kb0;
    bSrc1 = (const char*)(Wt + (bn0 + m_1) * Dm) + kb1;
  }
  auto stage = [&](int t, int buf) {
    char* base = smem + buf * 16384;
    const int kb = t * 64;
    gload16(aSrc0 + kb, base + wave * 1024);
    gload16(aSrc1 + kb, base + 4096 + wave * 1024);
    gload16(bSrc0 + kb, base + 8192 + wave * 1024);
    gload16(bSrc1 + kb, base + 12288 + wave * 1024);
  };

  int aOff[4], bOff[4];
#pragma unroll
  for (int i = 0; i < 4; ++i) {
    const int m = wr * 64 + i * 16 + r;
    const int lr = m >> 1;
    aOff[i] = lr * 128 + ((((m & 1) << 6) | (16 * g)) ^ ((lr & 7) << 4));
    const int n = wc * 64 + i * 16 + r;
    const int lrn = n >> 1;
    bOff[i] = 8192 + lrn * 128 + ((((n & 1) << 6) | (16 * g)) ^ ((lrn & 7) << 4));
  }

  float4v acc[4][4] = {};
  auto compute = [&](int buf) {
    const char* sb = smem + buf * 16384;
    short8 a[4], b[4];
#pragma unroll
    for (int i = 0; i < 4; ++i) a[i] = *(const short8*)(sb + aOff[i]);
#pragma unroll
    for (int i = 0; i < 4; ++i) b[i] = *(const short8*)(sb + bOff[i]);
#pragma unroll
    for (int mi = 0; mi < 4; ++mi)
#pragma unroll
      for (int ni = 0; ni < 4; ++ni)
        acc[mi][ni] = MFMA16(a[mi], b[ni], acc[mi][ni]);
  };

  stage(0, 0);
  stage(1, 1);
  stage(2, 2);
#pragma unroll 1
  for (int t = 0; t < 10; ++t) {  // 12 K-steps total
    asm volatile("s_waitcnt vmcnt(8)" ::: "memory");
    __builtin_amdgcn_s_barrier();
    compute(t % 3);
    __builtin_amdgcn_s_barrier();
    if (t < 9) stage(t + 3, t % 3);
  }
  asm volatile("s_waitcnt vmcnt(4)" ::: "memory");
  __builtin_amdgcn_s_barrier();
  compute(1);
  asm volatile("s_waitcnt vmcnt(0)" ::: "memory");
  __builtin_amdgcn_s_barrier();
  compute(2);

#pragma unroll
  for (int ni = 0; ni < 4; ++ni) {
    const int col = n0 + ni * 16 + r;
    const int p = col / 384, rr2 = col % 384;
    const int h = rr2 >> 6, dh = rr2 & 63;
    const float bv = bv_n[ni];
#pragma unroll
    for (int mi = 0; mi < 4; ++mi) {
#pragma unroll
      for (int rp = 0; rp < 2; ++rp) {
        const unsigned u = cvtpk(acc[mi][ni][2 * rp] + bv,
                                 acc[mi][ni][2 * rp + 1] + bv);
        const short lo = (short)u, hi = (short)(u >> 16);
        const int mg = m0 + mi * 16 + 4 * g + 2 * rp;
        if (p < 2) {
          qkv[mg * NQKV + col] = lo;
          qkv[(mg + 1) * NQKV + col] = hi;
        } else {
          const int bb = mg >> 10, s = mg & 1023;
          const int sp = vperm(s);  // pairs stay adjacent (s&3 in {0,2})
          short* vp = vt + ((bb * Hh + h) * Dh + dh) * Sq;
          vp[sp] = lo;
          vp[sp + 1] = hi;
        }
      }
    }
  }
}

// ---------------- attention v6: permuted-V b128 reads ----------------
// grid 768; 4 waves x 32 q-rows; KBLK=64; 2-buf 32KB LDS; vmcnt(4).
// V fragment = single ds_read_b128 (kv pre-permuted in vt by qkv_gemm).
__global__ __launch_bounds__(256) void attn(const short* __restrict__ qkv,
                                            const short* __restrict__ vt,
                                            short* __restrict__ ctx) {
  __shared__ char smem[32768];  // 2 bufs x (8KB K + 8KB V)
  const int tid = threadIdx.x;
  const int wave = tid >> 6, lane = tid & 63;
  const int r = lane & 15, g = lane >> 4;
  const int xr = (r & 7) << 4;
  // XCD-chunked swizzle: nwg = 768 = 8*96
  const int flat = blockIdx.x;
  const int w = (flat & 7) * 96 + (flat >> 3);
  const int qb = w & 7, bh = w >> 3;
  const int b = bh / Hh, h = bh % Hh;
  const int tok0 = b * Sq;
  const int qw = qb * 128 + wave * 32;

  short8 qf[2][2];
#pragma unroll
  for (int f = 0; f < 2; ++f) {
    const short* qp = qkv + (tok0 + qw + 16 * f + r) * NQKV + h * Dh;
    qf[f][0] = *(const short8*)(qp + 8 * g);
    qf[f][1] = *(const short8*)(qp + 32 + 8 * g);
  }
  asm volatile("s_waitcnt vmcnt(0)" ::: "memory");  // drain Q before DMA counting

  const short* kg = qkv + tok0 * NQKV + 384 + h * Dh;  // K rows, stride NQKV
  const short* vg = vt + (b * Hh + h) * Dh * Sq;       // V^T rows (kv-permuted)

  const int o0 = wave * 2048 + lane * 16;
  const int row0 = o0 >> 7, cb0 = (o0 & 127) ^ ((row0 & 7) << 4);
  const int o1 = o0 + 1024;
  const int row1 = o1 >> 7, cb1 = (o1 & 127) ^ ((row1 & 7) << 4);

#define STAGE(T, BUFSEL)                                                        \
  {                                                                             \
    char* kb_ = smem + (BUFSEL) * 16384;                                        \
    const int kv_ = (T) * 64;                                                   \
    gload16((const char*)(kg + (kv_ + row0) * NQKV) + cb0, kb_ + wave * 2048);  \
    gload16((const char*)(vg + row0 * Sq + kv_) + cb0, kb_ + 8192 + wave * 2048);\
    gload16((const char*)(kg + (kv_ + row1) * NQKV) + cb1, kb_ + wave * 2048 + 1024);\
    gload16((const char*)(vg + row1 * Sq + kv_) + cb1, kb_ + 8192 + wave * 2048 + 1024);\
  }

  int kOff[4][2], vOff[4][2];
#pragma unroll
  for (int kt = 0; kt < 4; ++kt)
#pragma unroll
    for (int c = 0; c < 2; ++c)
      kOff[kt][c] = (16 * kt + r) * 128 + ((64 * c + 16 * g) ^ xr);
#pragma unroll
  for (int d = 0; d < 4; ++d)
#pragma unroll
    for (int h2 = 0; h2 < 2; ++h2)
      vOff[d][h2] = (16 * d + r) * 128 + ((64 * h2 + 16 * g) ^ xr);

  float4v acc[4][2] = {};
  float lsum[2] = {0.f, 0.f};

  auto compute = [&](int bufsel) {
    const char* kb = smem + bufsel * 16384;
    const char* vb = kb + 8192;
    short8 kf[4][2];
#pragma unroll
    for (int kt = 0; kt < 4; ++kt) {
      kf[kt][0] = *(const short8*)(kb + kOff[kt][0]);
      kf[kt][1] = *(const short8*)(kb + kOff[kt][1]);
    }
    short8 vf[4][2];
#pragma unroll
    for (int d = 0; d < 4; ++d)
#pragma unroll
      for (int h2 = 0; h2 < 2; ++h2)
        vf[d][h2] = *(const short8*)(vb + vOff[d][h2]);
    float4v s[4][2];
    __builtin_amdgcn_s_setprio(1);
#pragma unroll
    for (int kt = 0; kt < 4; ++kt)
#pragma unroll
      for (int f = 0; f < 2; ++f) {
        float4v z = {};
        z = MFMA16(kf[kt][0], qf[f][0], z);
        z = MFMA16(kf[kt][1], qf[f][1], z);
        s[kt][f] = z;
      }
    __builtin_amdgcn_s_setprio(0);
    short8 pa[2][2];
#pragma unroll
    for (int f = 0; f < 2; ++f) {
      float ps = 0.f;
#pragma unroll
      for (int h2 = 0; h2 < 2; ++h2) {
        float e0[4], e1[4];
#pragma unroll
        for (int j = 0; j < 4; ++j) {
          e0[j] = EXP2(s[2 * h2][f][j]);
          e1[j] = EXP2(s[2 * h2 + 1][f][j]);
          ps += e0[j] + e1[j];
        }
        int4v wv;
        wv[0] = (int)cvtpk(e0[0], e0[1]);
        wv[1] = (int)cvtpk(e0[2], e0[3]);
        wv[2] = (int)cvtpk(e1[0], e1[1]);
        wv[3] = (int)cvtpk(e1[2], e1[3]);
        pa[f][h2] = __builtin_bit_cast(short8, wv);
      }
      lsum[f] += ps;
    }
    __builtin_amdgcn_s_setprio(1);
#pragma unroll
    for (int d = 0; d < 4; ++d)
#pragma unroll
      for (int f = 0; f < 2; ++f) {
        acc[d][f] = MFMA16(pa[f][0], vf[d][0], acc[d][f]);
        acc[d][f] = MFMA16(pa[f][1], vf[d][1], acc[d][f]);
      }
    __builtin_amdgcn_s_setprio(0);
  };

  STAGE(0, 0)
  STAGE(1, 1)
#pragma unroll 1
  for (int t = 0; t < 15; ++t) {
    asm volatile("s_waitcnt vmcnt(4)" ::: "memory");
    __builtin_amdgcn_s_barrier();
    compute(t & 1);
    __builtin_amdgcn_s_barrier();
    if (t < 14) STAGE(t + 2, t & 1)
  }
  asm volatile("s_waitcnt vmcnt(0)" ::: "memory");
  __builtin_amdgcn_s_barrier();
  compute(1);

#pragma unroll
  for (int f = 0; f < 2; ++f) {
    lsum[f] += __shfl_xor(lsum[f], 16);
    lsum[f] += __shfl_xor(lsum[f], 32);
  }
#pragma unroll
  for (int f = 0; f < 2; ++f) {
    float il[4];
#pragma unroll
    for (int reg = 0; reg < 4; ++reg) il[reg] = 1.f / __shfl(lsum[f], 4 * g + reg);
#pragma unroll
    for (int d = 0; d < 4; ++d) {
      short* cp = ctx + (tok0 + qw + 16 * f + 4 * g) * Dm + h * Dh + 16 * d + r;
#pragma unroll
      for (int reg = 0; reg < 4; ++reg)
        cp[reg * Dm] = f2bf(acc[d][f][reg] * il[reg]);
    }
  }
}

// ---------------- out-proj GEMM v4: BK=32, 3-deep pipeline ----------------
__global__ __launch_bounds__(256) void out_gemm(const short* __restrict__ ctx,
                                                const short* __restrict__ Wob,
                                                const float* __restrict__ bo,
                                                float* __restrict__ out) {
  __shared__ char smem[49152];
  const int tid = threadIdx.x;
  const int wave = tid >> 6, lane = tid & 63;
  const int r = lane & 15, g = lane >> 4;
  const int wr = wave >> 1, wc = wave & 1;

  // XCD-chunked bijective swizzle: nwg = 384 = 8*48
  const int flat = blockIdx.x;
  const int w = (flat & 7) * 48 + (flat >> 3);
  const int bx = w % 3, by = w / 3;
  const int bm0 = by * 128, bn0 = bx * 128;
  const int m0 = bm0 + wr * 64, n0 = bn0 + wc * 64;

  float bv_n[4];
#pragma unroll
  for (int ni = 0; ni < 4; ++ni) bv_n[ni] = bo[n0 + ni * 16 + r];
  asm volatile("s_waitcnt vmcnt(0)" ::: "memory");

  const char *aSrc0, *aSrc1, *bSrc0, *bSrc1;
  {
    const int o0 = tid * 16, o1 = 4096 + tid * 16;
    const int lr0 = o0 >> 7, cb0 = (o0 & 127) ^ ((lr0 & 7) << 4);
    const int lr1 = o1 >> 7, cb1 = (o1 & 127) ^ ((lr1 & 7) << 4);
    const int m_0 = 2 * lr0 + (cb0 >> 6), kb0 = cb0 & 63;
    const int m_1 = 2 * lr1 + (cb1 >> 6), kb1 = cb1 & 63;
    aSrc0 = (const char*)(ctx + (bm0 + m_0) * Dm) + kb0;
    aSrc1 = (const char*)(ctx + (bm0 + m_1) * Dm) + kb1;
    bSrc0 = (const char*)(Wob + (bn0 + m_0) * Dm) + kb0;
    bSrc1 = (const char*)(Wob + (bn0 + m_1) * Dm) + kb1;
  }
  auto stage = [&](int t, int buf) {
    char* base = smem + buf * 16384;
    const int kb = t * 64;
    gload16(aSrc0 + kb, base + wave * 1024);
    gload16(aSrc1 + kb, base + 4096 + wave * 1024);
    gload16(bSrc0 + kb, base + 8192 + wave * 1024);
    gload16(bSrc1 + kb, base + 12288 + wave * 1024);
  };

  int aOff[4], bOff[4];
#pragma unroll
  for (int i = 0; i < 4; ++i) {
    const int m = wr * 64 + i * 16 + r;
    const int lr = m >> 1;
    aOff[i] = lr * 128 + ((((m & 1) << 6) | (16 * g)) ^ ((lr & 7) << 4));
    const int n = wc * 64 + i * 16 + r;
    const int lrn = n >> 1;
    bOff[i] = 8192 + lrn * 128 + ((((n & 1) << 6) | (16 * g)) ^ ((lrn & 7) << 4));
  }

  float4v acc[4][4] = {};
  auto compute = [&](int buf) {
    const char* sb = smem + buf * 16384;
    short8 a[4], b[4];
#pragma unroll
    for (int i = 0; i < 4; ++i) a[i] = *(const short8*)(sb + aOff[i]);
#pragma unroll
    for (int i = 0; i < 4; ++i) b[i] = *(const short8*)(sb + bOff[i]);
#pragma unroll
    for (int mi = 0; mi < 4; ++mi)
#pragma unroll
      for (int ni = 0; ni < 4; ++ni)
        acc[mi][ni] = MFMA16(a[mi], b[ni], acc[mi][ni]);
  };

  stage(0, 0);
  stage(1, 1);
  stage(2, 2);
#pragma unroll 1
  for (int t = 0; t < 10; ++t) {
    asm volatile("s_waitcnt vmcnt(8)" ::: "memory");
    __builtin_amdgcn_s_barrier();
    compute(t % 3);
    __builtin_amdgcn_s_barrier();
    if (t < 9) stage(t + 3, t % 3);
  }
  asm volatile("s_waitcnt vmcnt(4)" ::: "memory");
  __builtin_amdgcn_s_barrier();
  compute(1);
  asm volatile("s_waitcnt vmcnt(0)" ::: "memory");
  __builtin_amdgcn_s_barrier();
  compute(2);

#pragma unroll
  for (int ni = 0; ni < 4; ++ni) {
    const int col = n0 + ni * 16 + r;
    const float bv = bv_n[ni];
#pragma unroll
    for (int mi = 0; mi < 4; ++mi) {
#pragma unroll
      for (int reg = 0; reg < 4; ++reg) {
        const int mg = m0 + mi * 16 + 4 * g + reg;
        out[mg * Dm + col] = acc[mi][ni][reg] + bv;
      }
    }
  }
}

extern "C" void kernel_launch(void* const* d_in, const int* in_sizes, int n_in,
                              void* d_out, int out_size, void* d_ws, size_t ws_size,
                              hipStream_t stream) {
  const float* x  = (const float*)d_in[0];
  const float* Wq = (const float*)d_in[1];
  const float* bq = (const float*)d_in[2];
  const float* Wk = (const float*)d_in[3];
  const float* bk = (const float*)d_in[4];
  const float* Wv = (const float*)d_in[5];
  const float* bv = (const float*)d_in[6];
  const float* Wo = (const float*)d_in[7];
  const float* bo = (const float*)d_in[8];
  float* out = (float*)d_out;

  char* ws = (char*)d_ws;
  short* Xb   = (short*)(ws);                  // 16384*384*2   = 12,582,912
  short* Wt   = (short*)(ws + 12582912);       // 1152*384*2    =    884,736
  float* bias = (float*)(ws + 13467648);       // 1152*4        =      4,608
  short* Wob  = (short*)(ws + 13472256);       // 384*384*2     =    294,912
  short* qkv  = (short*)(ws + 13767168);       // 16384*1152*2  = 37,748,736
  short* vt   = (short*)(ws + 51515904);       // 16*6*64*1024*2= 12,582,912
  short* ctx  = (short*)(ws + 64098816);       // 16384*384*2   = 12,582,912
  // total 76,681,728 bytes

  conv_x<<<Mtok * Dm / (256 * 8), 256, 0, stream>>>(x, Xb);
  conv_w<<<(NQKV * Dm + NQKV + Dm * Dm + 255) / 256, 256, 0, stream>>>(
      Wq, Wk, Wv, bq, bk, bv, Wo, Wt, bias, Wob);
  qkv_gemm<<<1152, 256, 0, stream>>>(Xb, Wt, bias, qkv, vt);
  attn<<<768, 256, 0, stream>>>(qkv, vt, ctx);
  out_gemm<<<384, 256, 0, stream>>>(ctx, Wob, bo, out);
}

// Round 8
// 97.016 us; speedup vs baseline: 1.2943x; 1.0347x over previous
//
#include <hip/hip_runtime.h>
#include <hip/hip_bf16.h>

typedef __attribute__((ext_vector_type(8))) short short8;
typedef __attribute__((ext_vector_type(4))) short short4v;
typedef __attribute__((ext_vector_type(4))) float float4v;
typedef __attribute__((ext_vector_type(4))) int int4v;

#define MFMA16(a,b,c) __builtin_amdgcn_mfma_f32_16x16x32_bf16((a),(b),(c),0,0,0)
#define EXP2(x) __builtin_amdgcn_exp2f(x)

static constexpr int Bz = 16, Sq = 1024, Dm = 384, Hh = 6, Dh = 64;
static constexpr int Mtok = Bz * Sq;     // 16384
static constexpr int NQKV = 1152;        // 3 * H * DH

__device__ __forceinline__ short f2bf(float f) {
  union { float f; unsigned u; } v; v.f = f;
  unsigned r = v.u + 0x7fffu + ((v.u >> 16) & 1u);  // RNE
  return (short)(r >> 16);
}

// packed f32x2 -> bf16x2 (lo = a, hi = b), RNE in HW
__device__ __forceinline__ unsigned cvtpk(float a, float b) {
  unsigned d;
  asm("v_cvt_pk_bf16_f32 %0, %1, %2" : "=v"(d) : "v"(a), "v"(b));
  return d;
}

__device__ __forceinline__ void gload16(const void* src, void* lds) {
  __builtin_amdgcn_global_load_lds(
      (const __attribute__((address_space(1))) unsigned int*)src,
      (__attribute__((address_space(3))) unsigned int*)lds, 16, 0, 0);
}

// kv-permutation within each 32-block: loc = 16hi+4grp+e -> 8grp+4hi+e.
// Makes each lane's PV B-fragment 16 CONTIGUOUS bytes -> single
// conflict-free ds_read_b128 in attn (verified R7: conflicts -> 0).
__device__ __forceinline__ int vperm(int s) {
  return (s & ~31) | ((s & 12) << 1) | ((s & 16) >> 2) | (s & 3);
}

// ---------------- prep: x fp32 -> bf16 ----------------
__global__ __launch_bounds__(256) void conv_x(const float* __restrict__ x,
                                              short* __restrict__ xb) {
  const int i = (blockIdx.x * 256 + threadIdx.x) * 8;  // total 6291456, exact
  float4v v0 = *(const float4v*)(x + i);
  float4v v1 = *(const float4v*)(x + i + 4);
  short8 o;
  o[0] = f2bf(v0[0]); o[1] = f2bf(v0[1]); o[2] = f2bf(v0[2]); o[3] = f2bf(v0[3]);
  o[4] = f2bf(v1[0]); o[5] = f2bf(v1[1]); o[6] = f2bf(v1[2]); o[7] = f2bf(v1[3]);
  *(short8*)(xb + i) = o;
}

// ---------------- prep: weights ----------------
__global__ __launch_bounds__(256) void conv_w(const float* __restrict__ Wq,
                                              const float* __restrict__ Wk,
                                              const float* __restrict__ Wv,
                                              const float* __restrict__ bq,
                                              const float* __restrict__ bk,
                                              const float* __restrict__ bv,
                                              const float* __restrict__ Wo,
                                              short* __restrict__ Wt,
                                              float* __restrict__ bias,
                                              short* __restrict__ Wob) {
  const float SCL = 0.125f * 1.44269504088896340736f;
  const int i = blockIdx.x * 256 + threadIdx.x;
  const int NW = NQKV * Dm;            // 442368
  if (i < NW) {
    const int c = i / Dm, d = i % Dm;
    const int p = c / 384, rr = c % 384;
    const int h = rr >> 6, dh = rr & 63;
    const float* W = (p == 0) ? Wq : ((p == 1) ? Wk : Wv);
    float w = W[(h * Dm + d) * Dh + dh];
    if (p == 0) w *= SCL;
    Wt[c * Dm + d] = f2bf(w);
  } else if (i < NW + NQKV) {
    const int c = i - NW;
    const int p = c / 384, rr = c % 384;
    const int h = rr >> 6, dh = rr & 63;
    const float* bb = (p == 0) ? bq : ((p == 1) ? bk : bv);
    float b = bb[h * Dh + dh];
    if (p == 0) b *= SCL;
    bias[c] = b;
  } else if (i < NW + NQKV + Dm * Dm) {
    const int j = i - NW - NQKV;
    Wob[j] = f2bf(Wo[j]);
  }
}

// Single-barrier 3-buffer pipeline (all MFMA kernels): prefetch depth 2,
// vmcnt(4) per tile, ONE s_barrier per tile. Stage at iter t targets buf
// (t+2)%3 = (t-1)%3 whose readers all retired before this iteration's
// barrier (ds_reads are register-consumed by MFMAs pre-barrier).

// ---------------- QKV GEMM v6: BK=32, 1-barrier 3-buf ----------------
__global__ __launch_bounds__(256) void qkv_gemm(const short* __restrict__ Xb,
                                                const short* __restrict__ Wt,
                                                const float* __restrict__ bias,
                                                short* __restrict__ qkv,
                                                short* __restrict__ vt) {
  __shared__ char smem[49152];  // 3 bufs x (8KB A + 8KB B)
  const int tid = threadIdx.x;
  const int wave = tid >> 6, lane = tid & 63;
  const int r = lane & 15, g = lane >> 4;
  const int wr = wave >> 1, wc = wave & 1;

  // XCD-chunked bijective swizzle: nwg = 1152 = 8*144
  const int flat = blockIdx.x;
  const int w = (flat & 7) * 144 + (flat >> 3);
  const int bx = w % 9, by = w / 9;
  const int bm0 = by * 128, bn0 = bx * 128;
  const int m0 = bm0 + wr * 64, n0 = bn0 + wc * 64;

  float bv_n[4];
#pragma unroll
  for (int ni = 0; ni < 4; ++ni) bv_n[ni] = bias[n0 + ni * 16 + r];
  asm volatile("s_waitcnt vmcnt(0)" ::: "memory");

  // staging source pointers (pre-swizzled)
  const char *aSrc0, *aSrc1, *bSrc0, *bSrc1;
  {
    const int o0 = tid * 16, o1 = 4096 + tid * 16;
    const int lr0 = o0 >> 7, cb0 = (o0 & 127) ^ ((lr0 & 7) << 4);
    const int lr1 = o1 >> 7, cb1 = (o1 & 127) ^ ((lr1 & 7) << 4);
    const int m_0 = 2 * lr0 + (cb0 >> 6), kb0 = cb0 & 63;
    const int m_1 = 2 * lr1 + (cb1 >> 6), kb1 = cb1 & 63;
    aSrc0 = (const char*)(Xb + (bm0 + m_0) * Dm) + kb0;
    aSrc1 = (const char*)(Xb + (bm0 + m_1) * Dm) + kb1;
    bSrc0 = (const char*)(Wt + (bn0 + m_0) * Dm) + kb0;
    bSrc1 = (const char*)(Wt + (bn0 + m_1) * Dm) + kb1;
  }
  auto stage = [&](int t, int buf) {
    char* base = smem + buf * 16384;
    const int kb = t * 64;
    gload16(aSrc0 + kb, base + wave * 1024);
    gload16(aSrc1 + kb, base + 4096 + wave * 1024);
    gload16(bSrc0 + kb, base + 8192 + wave * 1024);
    gload16(bSrc1 + kb, base + 12288 + wave * 1024);
  };

  int aOff[4], bOff[4];
#pragma unroll
  for (int i = 0; i < 4; ++i) {
    const int m = wr * 64 + i * 16 + r;
    const int lr = m >> 1;
    aOff[i] = lr * 128 + ((((m & 1) << 6) | (16 * g)) ^ ((lr & 7) << 4));
    const int n = wc * 64 + i * 16 + r;
    const int lrn = n >> 1;
    bOff[i] = 8192 + lrn * 128 + ((((n & 1) << 6) | (16 * g)) ^ ((lrn & 7) << 4));
  }

  float4v acc[4][4] = {};
  auto compute = [&](int buf) {
    const char* sb = smem + buf * 16384;
    short8 a[4], b[4];
#pragma unroll
    for (int i = 0; i < 4; ++i) a[i] = *(const short8*)(sb + aOff[i]);
#pragma unroll
    for (int i = 0; i < 4; ++i) b[i] = *(const short8*)(sb + bOff[i]);
#pragma unroll
    for (int mi = 0; mi < 4; ++mi)
#pragma unroll
      for (int ni = 0; ni < 4; ++ni)
        acc[mi][ni] = MFMA16(a[mi], b[ni], acc[mi][ni]);
  };

  stage(0, 0);
  stage(1, 1);
#pragma unroll 1
  for (int t = 0; t < 10; ++t) {  // 12 K-steps total
    asm volatile("s_waitcnt vmcnt(4)" ::: "memory");
    __builtin_amdgcn_s_barrier();
    compute(t % 3);
    stage(t + 2, (t + 2) % 3);
  }
  asm volatile("s_waitcnt vmcnt(4)" ::: "memory");
  __builtin_amdgcn_s_barrier();
  compute(1);
  asm volatile("s_waitcnt vmcnt(0)" ::: "memory");
  __builtin_amdgcn_s_barrier();
  compute(2);

#pragma unroll
  for (int ni = 0; ni < 4; ++ni) {
    const int col = n0 + ni * 16 + r;
    const int p = col / 384, rr2 = col % 384;
    const int h = rr2 >> 6, dh = rr2 & 63;
    const float bv = bv_n[ni];
#pragma unroll
    for (int mi = 0; mi < 4; ++mi) {
#pragma unroll
      for (int rp = 0; rp < 2; ++rp) {
        const unsigned u = cvtpk(acc[mi][ni][2 * rp] + bv,
                                 acc[mi][ni][2 * rp + 1] + bv);
        const short lo = (short)u, hi = (short)(u >> 16);
        const int mg = m0 + mi * 16 + 4 * g + 2 * rp;
        if (p < 2) {
          qkv[mg * NQKV + col] = lo;
          qkv[(mg + 1) * NQKV + col] = hi;
        } else {
          const int bb = mg >> 10, s = mg & 1023;
          const int sp = vperm(s);  // pairs stay adjacent (s&3 in {0,2})
          short* vp = vt + ((bb * Hh + h) * Dh + dh) * Sq;
          vp[sp] = lo;
          vp[sp + 1] = hi;
        }
      }
    }
  }
}

// ---------------- attention v7: 1-barrier 3-buf + MFMA row-sum ----------------
// grid 768; 4 waves x 32 q-rows; KBLK=64. V fragment = single ds_read_b128
// (kv pre-permuted in vt). Row-sum of P via MFMA against all-ones B operand:
// removes the ps-add chain and ALL end-of-kernel shuffles.
__global__ __launch_bounds__(256) void attn(const short* __restrict__ qkv,
                                            const short* __restrict__ vt,
                                            short* __restrict__ ctx) {
  __shared__ char smem[49152];  // 3 bufs x (8KB K + 8KB V)
  const int tid = threadIdx.x;
  const int wave = tid >> 6, lane = tid & 63;
  const int r = lane & 15, g = lane >> 4;
  const int xr = (r & 7) << 4;
  // XCD-chunked swizzle: nwg = 768 = 8*96
  const int flat = blockIdx.x;
  const int w = (flat & 7) * 96 + (flat >> 3);
  const int qb = w & 7, bh = w >> 3;
  const int b = bh / Hh, h = bh % Hh;
  const int tok0 = b * Sq;
  const int qw = qb * 128 + wave * 32;

  short8 qf[2][2];
#pragma unroll
  for (int f = 0; f < 2; ++f) {
    const short* qp = qkv + (tok0 + qw + 16 * f + r) * NQKV + h * Dh;
    qf[f][0] = *(const short8*)(qp + 8 * g);
    qf[f][1] = *(const short8*)(qp + 32 + 8 * g);
  }
  asm volatile("s_waitcnt vmcnt(0)" ::: "memory");  // drain Q before DMA counting

  const short* kg = qkv + tok0 * NQKV + 384 + h * Dh;  // K rows, stride NQKV
  const short* vg = vt + (b * Hh + h) * Dh * Sq;       // V^T rows (kv-permuted)

  const int o0 = wave * 2048 + lane * 16;
  const int row0 = o0 >> 7, cb0 = (o0 & 127) ^ ((row0 & 7) << 4);
  const int o1 = o0 + 1024;
  const int row1 = o1 >> 7, cb1 = (o1 & 127) ^ ((row1 & 7) << 4);

#define STAGE(T, BUFSEL)                                                        \
  {                                                                             \
    char* kb_ = smem + (BUFSEL) * 16384;                                        \
    const int kv_ = (T) * 64;                                                   \
    gload16((const char*)(kg + (kv_ + row0) * NQKV) + cb0, kb_ + wave * 2048);  \
    gload16((const char*)(vg + row0 * Sq + kv_) + cb0, kb_ + 8192 + wave * 2048);\
    gload16((const char*)(kg + (kv_ + row1) * NQKV) + cb1, kb_ + wave * 2048 + 1024);\
    gload16((const char*)(vg + row1 * Sq + kv_) + cb1, kb_ + 8192 + wave * 2048 + 1024);\
  }

  int kOff[4][2], vOff[4][2];
#pragma unroll
  for (int kt = 0; kt < 4; ++kt)
#pragma unroll
    for (int c = 0; c < 2; ++c)
      kOff[kt][c] = (16 * kt + r) * 128 + ((64 * c + 16 * g) ^ xr);
#pragma unroll
  for (int d = 0; d < 4; ++d)
#pragma unroll
    for (int h2 = 0; h2 < 2; ++h2)
      vOff[d][h2] = (16 * d + r) * 128 + ((64 * h2 + 16 * g) ^ xr);

  short8 ones;
#pragma unroll
  for (int j = 0; j < 8; ++j) ones[j] = (short)0x3F80;  // bf16 1.0

  float4v acc[4][2] = {};
  float4v lacc[2] = {};

  auto compute = [&](int bufsel) {
    const char* kb = smem + bufsel * 16384;
    const char* vb = kb + 8192;
    short8 kf[4][2];
#pragma unroll
    for (int kt = 0; kt < 4; ++kt) {
      kf[kt][0] = *(const short8*)(kb + kOff[kt][0]);
      kf[kt][1] = *(const short8*)(kb + kOff[kt][1]);
    }
    short8 vf[4][2];
#pragma unroll
    for (int d = 0; d < 4; ++d)
#pragma unroll
      for (int h2 = 0; h2 < 2; ++h2)
        vf[d][h2] = *(const short8*)(vb + vOff[d][h2]);
    float4v s[4][2];
    __builtin_amdgcn_s_setprio(1);
#pragma unroll
    for (int kt = 0; kt < 4; ++kt)
#pragma unroll
      for (int f = 0; f < 2; ++f) {
        float4v z = {};
        z = MFMA16(kf[kt][0], qf[f][0], z);
        z = MFMA16(kf[kt][1], qf[f][1], z);
        s[kt][f] = z;
      }
    __builtin_amdgcn_s_setprio(0);
    short8 pa[2][2];
#pragma unroll
    for (int f = 0; f < 2; ++f)
#pragma unroll
      for (int h2 = 0; h2 < 2; ++h2) {
        int4v wv;
        wv[0] = (int)cvtpk(EXP2(s[2 * h2][f][0]), EXP2(s[2 * h2][f][1]));
        wv[1] = (int)cvtpk(EXP2(s[2 * h2][f][2]), EXP2(s[2 * h2][f][3]));
        wv[2] = (int)cvtpk(EXP2(s[2 * h2 + 1][f][0]), EXP2(s[2 * h2 + 1][f][1]));
        wv[3] = (int)cvtpk(EXP2(s[2 * h2 + 1][f][2]), EXP2(s[2 * h2 + 1][f][3]));
        pa[f][h2] = __builtin_bit_cast(short8, wv);
      }
    __builtin_amdgcn_s_setprio(1);
#pragma unroll
    for (int d = 0; d < 4; ++d)
#pragma unroll
      for (int f = 0; f < 2; ++f) {
        acc[d][f] = MFMA16(pa[f][0], vf[d][0], acc[d][f]);
        acc[d][f] = MFMA16(pa[f][1], vf[d][1], acc[d][f]);
      }
#pragma unroll
    for (int f = 0; f < 2; ++f) {
      lacc[f] = MFMA16(pa[f][0], ones, lacc[f]);
      lacc[f] = MFMA16(pa[f][1], ones, lacc[f]);
    }
    __builtin_amdgcn_s_setprio(0);
  };

  STAGE(0, 0)
  STAGE(1, 1)
#pragma unroll 1
  for (int t = 0; t < 14; ++t) {
    asm volatile("s_waitcnt vmcnt(4)" ::: "memory");
    __builtin_amdgcn_s_barrier();
    compute(t % 3);
    STAGE(t + 2, (t + 2) % 3)
  }
  asm volatile("s_waitcnt vmcnt(4)" ::: "memory");
  __builtin_amdgcn_s_barrier();
  compute(2);   // tile 14
  asm volatile("s_waitcnt vmcnt(0)" ::: "memory");
  __builtin_amdgcn_s_barrier();
  compute(0);   // tile 15

#pragma unroll
  for (int f = 0; f < 2; ++f) {
    float il[4];
#pragma unroll
    for (int reg = 0; reg < 4; ++reg) il[reg] = 1.f / lacc[f][reg];
#pragma unroll
    for (int d = 0; d < 4; ++d) {
      short* cp = ctx + (tok0 + qw + 16 * f + 4 * g) * Dm + h * Dh + 16 * d + r;
#pragma unroll
      for (int reg = 0; reg < 4; ++reg)
        cp[reg * Dm] = f2bf(acc[d][f][reg] * il[reg]);
    }
  }
}

// ---------------- out-proj GEMM v5: BK=32, 1-barrier 3-buf ----------------
__global__ __launch_bounds__(256) void out_gemm(const short* __restrict__ ctx,
                                                const short* __restrict__ Wob,
                                                const float* __restrict__ bo,
                                                float* __restrict__ out) {
  __shared__ char smem[49152];
  const int tid = threadIdx.x;
  const int wave = tid >> 6, lane = tid & 63;
  const int r = lane & 15, g = lane >> 4;
  const int wr = wave >> 1, wc = wave & 1;

  // XCD-chunked bijective swizzle: nwg = 384 = 8*48
  const int flat = blockIdx.x;
  const int w = (flat & 7) * 48 + (flat >> 3);
  const int bx = w % 3, by = w / 3;
  const int bm0 = by * 128, bn0 = bx * 128;
  const int m0 = bm0 + wr * 64, n0 = bn0 + wc * 64;

  float bv_n[4];
#pragma unroll
  for (int ni = 0; ni < 4; ++ni) bv_n[ni] = bo[n0 + ni * 16 + r];
  asm volatile("s_waitcnt vmcnt(0)" ::: "memory");

  const char *aSrc0, *aSrc1, *bSrc0, *bSrc1;
  {
    const int o0 = tid * 16, o1 = 4096 + tid * 16;
    const int lr0 = o0 >> 7, cb0 = (o0 & 127) ^ ((lr0 & 7) << 4);
    const int lr1 = o1 >> 7, cb1 = (o1 & 127) ^ ((lr1 & 7) << 4);
    const int m_0 = 2 * lr0 + (cb0 >> 6), kb0 = cb0 & 63;
    const int m_1 = 2 * lr1 + (cb1 >> 6), kb1 = cb1 & 63;
    aSrc0 = (const char*)(ctx + (bm0 + m_0) * Dm) + kb0;
    aSrc1 = (const char*)(ctx + (bm0 + m_1) * Dm) + kb1;
    bSrc0 = (const char*)(Wob + (bn0 + m_0) * Dm) + kb0;
    bSrc1 = (const char*)(Wob + (bn0 + m_1) * Dm) + kb1;
  }
  auto stage = [&](int t, int buf) {
    char* base = smem + buf * 16384;
    const int kb = t * 64;
    gload16(aSrc0 + kb, base + wave * 1024);
    gload16(aSrc1 + kb, base + 4096 + wave * 1024);
    gload16(bSrc0 + kb, base + 8192 + wave * 1024);
    gload16(bSrc1 + kb, base + 12288 + wave * 1024);
  };

  int aOff[4], bOff[4];
#pragma unroll
  for (int i = 0; i < 4; ++i) {
    const int m = wr * 64 + i * 16 + r;
    const int lr = m >> 1;
    aOff[i] = lr * 128 + ((((m & 1) << 6) | (16 * g)) ^ ((lr & 7) << 4));
    const int n = wc * 64 + i * 16 + r;
    const int lrn = n >> 1;
    bOff[i] = 8192 + lrn * 128 + ((((n & 1) << 6) | (16 * g)) ^ ((lrn & 7) << 4));
  }

  float4v acc[4][4] = {};
  auto compute = [&](int buf) {
    const char* sb = smem + buf * 16384;
    short8 a[4], b[4];
#pragma unroll
    for (int i = 0; i < 4; ++i) a[i] = *(const short8*)(sb + aOff[i]);
#pragma unroll
    for (int i = 0; i < 4; ++i) b[i] = *(const short8*)(sb + bOff[i]);
#pragma unroll
    for (int mi = 0; mi < 4; ++mi)
#pragma unroll
      for (int ni = 0; ni < 4; ++ni)
        acc[mi][ni] = MFMA16(a[mi], b[ni], acc[mi][ni]);
  };

  stage(0, 0);
  stage(1, 1);
#pragma unroll 1
  for (int t = 0; t < 10; ++t) {
    asm volatile("s_waitcnt vmcnt(4)" ::: "memory");
    __builtin_amdgcn_s_barrier();
    compute(t % 3);
    stage(t + 2, (t + 2) % 3);
  }
  asm volatile("s_waitcnt vmcnt(4)" ::: "memory");
  __builtin_amdgcn_s_barrier();
  compute(1);
  asm volatile("s_waitcnt vmcnt(0)" ::: "memory");
  __builtin_amdgcn_s_barrier();
  compute(2);

#pragma unroll
  for (int ni = 0; ni < 4; ++ni) {
    const int col = n0 + ni * 16 + r;
    const float bv = bv_n[ni];
#pragma unroll
    for (int mi = 0; mi < 4; ++mi) {
#pragma unroll
      for (int reg = 0; reg < 4; ++reg) {
        const int mg = m0 + mi * 16 + 4 * g + reg;
        out[mg * Dm + col] = acc[mi][ni][reg] + bv;
      }
    }
  }
}

extern "C" void kernel_launch(void* const* d_in, const int* in_sizes, int n_in,
                              void* d_out, int out_size, void* d_ws, size_t ws_size,
                              hipStream_t stream) {
  const float* x  = (const float*)d_in[0];
  const float* Wq = (const float*)d_in[1];
  const float* bq = (const float*)d_in[2];
  const float* Wk = (const float*)d_in[3];
  const float* bk = (const float*)d_in[4];
  const float* Wv = (const float*)d_in[5];
  const float* bv = (const float*)d_in[6];
  const float* Wo = (const float*)d_in[7];
  const float* bo = (const float*)d_in[8];
  float* out = (float*)d_out;

  char* ws = (char*)d_ws;
  short* Xb   = (short*)(ws);                  // 16384*384*2   = 12,582,912
  short* Wt   = (short*)(ws + 12582912);       // 1152*384*2    =    884,736
  float* bias = (float*)(ws + 13467648);       // 1152*4        =      4,608
  short* Wob  = (short*)(ws + 13472256);       // 384*384*2     =    294,912
  short* qkv  = (short*)(ws + 13767168);       // 16384*1152*2  = 37,748,736
  short* vt   = (short*)(ws + 51515904);       // 16*6*64*1024*2= 12,582,912
  short* ctx  = (short*)(ws + 64098816);       // 16384*384*2   = 12,582,912
  // total 76,681,728 bytes

  conv_x<<<Mtok * Dm / (256 * 8), 256, 0, stream>>>(x, Xb);
  conv_w<<<(NQKV * Dm + NQKV + Dm * Dm + 255) / 256, 256, 0, stream>>>(
      Wq, Wk, Wv, bq, bk, bv, Wo, Wt, bias, Wob);
  qkv_gemm<<<1152, 256, 0, stream>>>(Xb, Wt, bias, qkv, vt);
  attn<<<768, 256, 0, stream>>>(qkv, vt, ctx);
  out_gemm<<<384, 256, 0, stream>>>(ctx, Wob, bo, out);
}